// Round 3
// baseline (154.186 us; speedup 1.0000x reference)
//
#include <hip/hip_runtime.h>
#include <math.h>
#include <stdint.h>

// Problem constants (from reference setup_inputs)
static constexpr int B_TOTAL = 131072;
static constexpr int M_MOD   = 14;    // NB_MOD_MAX + 2
static constexpr int C_DIM   = 128;   // CONCEPT_N

// Binning: uid in [0,100000) -> bin = uid>>7 (782 bins, padded to 1024).
// Each bin covers a 128-row = 64 KB window of users_emb -> DRAM row locality
// + duplicate-user L2 hits when processed bin-contiguously.
static constexpr int NBINS    = 1024;
static constexpr int BIN_CAP  = 256;              // mean fill ~168, max ~230
static constexpr int NSLOTS   = NBINS * BIN_CAP;  // 262144 slots
static constexpr int BIN_BLKS = NSLOTS / 16;      // 16384 blocks, 16 slots each
static constexpr int OVF_BLKS = B_TOTAL / 16;     // full coverage of overflow

// ws layout (bytes):
//   [0)        cnt[NBINS+1]  (bin counters + overflow counter)  4100 B
//   [8192)     slots[NSLOTS] uint64  (uid<<32 | e)              2 MiB
//   [8192+2Mi) ovf[B_TOTAL]  uint64                             1 MiB
static constexpr size_t WS_SLOTS_OFF = 8192;
static constexpr size_t WS_OVF_OFF   = WS_SLOTS_OFF + (size_t)NSLOTS * 8;
static constexpr size_t WS_NEEDED    = WS_OVF_OFF + (size_t)B_TOTAL * 8;

__global__ __launch_bounds__(1024) void zero_kernel(uint32_t* __restrict__ cnt) {
    const int i = threadIdx.x;
    cnt[i] = 0u;
    if (i == 0) cnt[NBINS] = 0u;
}

__global__ __launch_bounds__(256) void scatter_kernel(
    const int* __restrict__ user_ids,
    uint32_t*  __restrict__ cnt,
    uint64_t*  __restrict__ slots,
    uint64_t*  __restrict__ ovf)
{
    const int e   = blockIdx.x * 256 + threadIdx.x;
    const int uid = user_ids[e];
    const int bin = uid >> 7;
    const uint64_t pk = ((uint64_t)(uint32_t)uid << 32) | (uint32_t)e;
    const uint32_t r = atomicAdd(&cnt[bin], 1u);
    if (r < (uint32_t)BIN_CAP) {
        slots[(size_t)bin * BIN_CAP + r] = pk;
    } else {
        const uint32_t o = atomicAdd(&cnt[NBINS], 1u);  // cap B_TOTAL: safe
        ovf[o] = pk;
    }
}

// Main kernel: one 16-lane group per slot (batch element), processed in
// bin-sorted order. Per-element math identical to the verified kernel:
// argmin_j ||u - im_j||^2 = argmin_j ( P_j^T G P_j - 2 P_j . v ),
// v = W_t u, G = W_t W_t^T; lane s owns 8 concept cols, scores j=s+1;
// ballot/ctz gives jnp.argmin's lowest-index tiebreak.
__global__ __launch_bounds__(256) void impact_binned(
    const int*      __restrict__ item_ids,
    const int*      __restrict__ concept_ids,
    const float*    __restrict__ users_emb,   // (USER_N, 128)
    const float*    __restrict__ item_resp,   // (ITEM_N * 14, 3)
    const float*    __restrict__ W,           // (128, 3, 128)
    const int*      __restrict__ nb_mod,      // (ITEM_N,)
    const uint32_t* __restrict__ cnt,
    const uint64_t* __restrict__ slots,
    const uint64_t* __restrict__ ovf,
    float*          __restrict__ out)
{
    const int s = threadIdx.x & 15;   // sublane in group
    const int g = threadIdx.x >> 4;   // group in block (0..15)

    uint64_t pk;
    if (blockIdx.x < BIN_BLKS) {
        const int bin  = blockIdx.x >> 4;          // 16 blocks per bin
        const int base = (blockIdx.x & 15) * 16;   // slot-in-bin base
        uint32_t n = cnt[bin];
        if (n > (uint32_t)BIN_CAP) n = BIN_CAP;
        if ((uint32_t)(base + g) >= n) return;     // idle group / idle block
        pk = slots[(size_t)bin * BIN_CAP + base + g];
    } else {
        const uint32_t base = (uint32_t)(blockIdx.x - BIN_BLKS) * 16u;
        const uint32_t n = cnt[NBINS];
        if (base + (uint32_t)g >= n) return;
        pk = ovf[base + g];
    }

    const int e   = (int)(uint32_t)pk;
    const int uid = (int)(uint32_t)(pk >> 32);
    const int iid = item_ids[e];
    const int cid = concept_ids[e];
    const int nb  = nb_mod[iid];

    // Branchless P load: lane s scores modality j=s+1; lanes 12..15 clamp to
    // j=1 (score masked to INF below).
    const int jl = (s < 12) ? (s + 1) : 1;
    const float* pj = item_resp + ((size_t)iid * M_MOD + jl) * 3;
    const float p0 = pj[0], p1 = pj[1], p2 = pj[2];

    // u row: 2 x float4 per lane (contiguous 256 B runs per group).
    const float4* up = (const float4*)(users_emb + (size_t)uid * C_DIM);
    const float4 uA = up[s], uB = up[s + 16];
    // W_t = W[cid]: 3 rows x 512 B (L2-resident 196 KB table).
    const float4* wp = (const float4*)(W + (size_t)cid * 3 * C_DIM);
    const float4 w0a = wp[s],      w0b = wp[16 + s];
    const float4 w1a = wp[32 + s], w1b = wp[48 + s];
    const float4 w2a = wp[64 + s], w2b = wp[80 + s];

    float v0 = 0.f, v1 = 0.f, v2 = 0.f;
    float g00 = 0.f, g01 = 0.f, g02 = 0.f, g11 = 0.f, g12 = 0.f, g22 = 0.f;
#define COL(uc, a0, a1, a2)                                                    \
    do {                                                                       \
        v0  = fmaf((a0), (uc), v0);  v1  = fmaf((a1), (uc), v1);               \
        v2  = fmaf((a2), (uc), v2);                                            \
        g00 = fmaf((a0), (a0), g00); g01 = fmaf((a0), (a1), g01);              \
        g02 = fmaf((a0), (a2), g02); g11 = fmaf((a1), (a1), g11);              \
        g12 = fmaf((a1), (a2), g12); g22 = fmaf((a2), (a2), g22);              \
    } while (0)
    COL(uA.x, w0a.x, w1a.x, w2a.x);
    COL(uA.y, w0a.y, w1a.y, w2a.y);
    COL(uA.z, w0a.z, w1a.z, w2a.z);
    COL(uA.w, w0a.w, w1a.w, w2a.w);
    COL(uB.x, w0b.x, w1b.x, w2b.x);
    COL(uB.y, w0b.y, w1b.y, w2b.y);
    COL(uB.z, w0b.z, w1b.z, w2b.z);
    COL(uB.w, w0b.w, w1b.w, w2b.w);
#undef COL

#pragma unroll
    for (int off = 8; off; off >>= 1) {
        v0  += __shfl_xor(v0,  off, 64);
        v1  += __shfl_xor(v1,  off, 64);
        v2  += __shfl_xor(v2,  off, 64);
        g00 += __shfl_xor(g00, off, 64);
        g01 += __shfl_xor(g01, off, 64);
        g02 += __shfl_xor(g02, off, 64);
        g11 += __shfl_xor(g11, off, 64);
        g12 += __shfl_xor(g12, off, 64);
        g22 += __shfl_xor(g22, off, 64);
    }

    float m = INFINITY;
    if (s < 12 && (s + 1) <= nb) {
        const float dot = fmaf(p0, v0, fmaf(p1, v1, p2 * v2));
        float q = p0 * p0 * g00;
        q = fmaf(p1 * p1, g11, q);
        q = fmaf(p2 * p2, g22, q);
        q = fmaf(2.0f * p0 * p1, g01, q);
        q = fmaf(2.0f * p0 * p2, g02, q);
        q = fmaf(2.0f * p1 * p2, g12, q);
        m = fmaf(-2.0f, dot, q);
    }
    float bm = m;
#pragma unroll
    for (int off = 8; off; off >>= 1)
        bm = fminf(bm, __shfl_xor(bm, off, 64));
    const unsigned long long mask = __ballot(m == bm);
    if (s == 0) {
        const int grp = g & 3;
        const unsigned slice = (unsigned)((mask >> (grp * 16)) & 0xffffu);
        const int jm1 = __builtin_ctz(slice);   // lane s <-> j=s+1
        out[e] = (float)jm1 / (float)(nb - 1) + 1.0f;
    }
}

// Fallback (ws too small): the previously verified direct kernel.
__global__ __launch_bounds__(256) void impact_direct(
    const int*   __restrict__ user_ids,
    const int*   __restrict__ item_ids,
    const int*   __restrict__ concept_ids,
    const float* __restrict__ users_emb,
    const float* __restrict__ item_resp,
    const float* __restrict__ W,
    const int*   __restrict__ nb_mod,
    float*       __restrict__ out)
{
    const int s = threadIdx.x & 15;
    const int b = blockIdx.x * 16 + (threadIdx.x >> 4);

    const int uid = user_ids[b];
    const int iid = item_ids[b];
    const int cid = concept_ids[b];
    const int nb  = nb_mod[iid];

    const int jl = (s < 12) ? (s + 1) : 1;
    const float* pj = item_resp + ((size_t)iid * M_MOD + jl) * 3;
    const float p0 = pj[0], p1 = pj[1], p2 = pj[2];

    const float4* up = (const float4*)(users_emb + (size_t)uid * C_DIM);
    const float4 uA = up[s], uB = up[s + 16];
    const float4* wp = (const float4*)(W + (size_t)cid * 3 * C_DIM);
    const float4 w0a = wp[s],      w0b = wp[16 + s];
    const float4 w1a = wp[32 + s], w1b = wp[48 + s];
    const float4 w2a = wp[64 + s], w2b = wp[80 + s];

    float v0 = 0.f, v1 = 0.f, v2 = 0.f;
    float g00 = 0.f, g01 = 0.f, g02 = 0.f, g11 = 0.f, g12 = 0.f, g22 = 0.f;
#define COL(uc, a0, a1, a2)                                                    \
    do {                                                                       \
        v0  = fmaf((a0), (uc), v0);  v1  = fmaf((a1), (uc), v1);               \
        v2  = fmaf((a2), (uc), v2);                                            \
        g00 = fmaf((a0), (a0), g00); g01 = fmaf((a0), (a1), g01);              \
        g02 = fmaf((a0), (a2), g02); g11 = fmaf((a1), (a1), g11);              \
        g12 = fmaf((a1), (a2), g12); g22 = fmaf((a2), (a2), g22);              \
    } while (0)
    COL(uA.x, w0a.x, w1a.x, w2a.x);
    COL(uA.y, w0a.y, w1a.y, w2a.y);
    COL(uA.z, w0a.z, w1a.z, w2a.z);
    COL(uA.w, w0a.w, w1a.w, w2a.w);
    COL(uB.x, w0b.x, w1b.x, w2b.x);
    COL(uB.y, w0b.y, w1b.y, w2b.y);
    COL(uB.z, w0b.z, w1b.z, w2b.z);
    COL(uB.w, w0b.w, w1b.w, w2b.w);
#undef COL
#pragma unroll
    for (int off = 8; off; off >>= 1) {
        v0  += __shfl_xor(v0,  off, 64);
        v1  += __shfl_xor(v1,  off, 64);
        v2  += __shfl_xor(v2,  off, 64);
        g00 += __shfl_xor(g00, off, 64);
        g01 += __shfl_xor(g01, off, 64);
        g02 += __shfl_xor(g02, off, 64);
        g11 += __shfl_xor(g11, off, 64);
        g12 += __shfl_xor(g12, off, 64);
        g22 += __shfl_xor(g22, off, 64);
    }
    float m = INFINITY;
    if (s < 12 && (s + 1) <= nb) {
        const float dot = fmaf(p0, v0, fmaf(p1, v1, p2 * v2));
        float q = p0 * p0 * g00;
        q = fmaf(p1 * p1, g11, q);
        q = fmaf(p2 * p2, g22, q);
        q = fmaf(2.0f * p0 * p1, g01, q);
        q = fmaf(2.0f * p0 * p2, g02, q);
        q = fmaf(2.0f * p1 * p2, g12, q);
        m = fmaf(-2.0f, dot, q);
    }
    float bm = m;
#pragma unroll
    for (int off = 8; off; off >>= 1)
        bm = fminf(bm, __shfl_xor(bm, off, 64));
    const unsigned long long mask = __ballot(m == bm);
    if (s == 0) {
        const int grp = (threadIdx.x >> 4) & 3;
        const unsigned slice = (unsigned)((mask >> (grp * 16)) & 0xffffu);
        const int jm1 = __builtin_ctz(slice);
        out[b] = (float)jm1 / (float)(nb - 1) + 1.0f;
    }
}

extern "C" void kernel_launch(void* const* d_in, const int* in_sizes, int n_in,
                              void* d_out, int out_size, void* d_ws, size_t ws_size,
                              hipStream_t stream) {
    const int*   user_ids    = (const int*)d_in[0];
    const int*   item_ids    = (const int*)d_in[1];
    const int*   concept_ids = (const int*)d_in[2];
    const float* users_emb   = (const float*)d_in[3];
    const float* item_resp   = (const float*)d_in[4];
    const float* W           = (const float*)d_in[5];
    // d_in[6] = mask: unused — validity recomputed from nb_modalities.
    const int*   nb_mod      = (const int*)d_in[7];
    float*       out         = (float*)d_out;

    if (d_ws != nullptr && ws_size >= WS_NEEDED) {
        uint32_t* cnt   = (uint32_t*)d_ws;
        uint64_t* slots = (uint64_t*)((char*)d_ws + WS_SLOTS_OFF);
        uint64_t* ovf   = (uint64_t*)((char*)d_ws + WS_OVF_OFF);
        zero_kernel<<<dim3(1), dim3(1024), 0, stream>>>(cnt);
        scatter_kernel<<<dim3(B_TOTAL / 256), dim3(256), 0, stream>>>(
            user_ids, cnt, slots, ovf);
        impact_binned<<<dim3(BIN_BLKS + OVF_BLKS), dim3(256), 0, stream>>>(
            item_ids, concept_ids, users_emb, item_resp, W, nb_mod,
            cnt, slots, ovf, out);
    } else {
        impact_direct<<<dim3(B_TOTAL / 16), dim3(256), 0, stream>>>(
            user_ids, item_ids, concept_ids, users_emb, item_resp, W, nb_mod,
            out);
    }
}

// Round 4
// 112.492 us; speedup vs baseline: 1.3706x; 1.3706x over previous
//
#include <hip/hip_runtime.h>
#include <math.h>

// Problem constants (from reference setup_inputs)
static constexpr int B_TOTAL   = 131072;
static constexpr int M_MOD     = 14;    // NB_MOD_MAX + 2
static constexpr int C_DIM     = 128;   // CONCEPT_N
static constexpr int CONCEPT_N = 128;

// ---------------------------------------------------------------------------
// Prepass: Gram matrices G[c] = W[c] (3x128) * W[c]^T -> 6 floats, padded to
// 8 per concept (2 x float4), in workspace. Verified absmax=0.0 in round 1.
// Purpose HERE: shrink the main kernel's register footprint (no 6 Gram
// accumulators, reduce only 3 values instead of 9) so it fits the 64-VGPR
// budget required for 8 waves/SIMD occupancy.
// ---------------------------------------------------------------------------
__global__ __launch_bounds__(64) void gram_kernel(
    const float* __restrict__ W,   // (128, 3, 128)
    float*       __restrict__ Gt)  // (128, 8)
{
    const int c = blockIdx.x;      // concept id
    const int l = threadIdx.x;     // 0..63
    const float* wp = W + (size_t)c * 3 * C_DIM;
    float g00 = 0.f, g01 = 0.f, g02 = 0.f, g11 = 0.f, g12 = 0.f, g22 = 0.f;
#pragma unroll
    for (int k = 0; k < 2; ++k) {
        const int col = l + 64 * k;
        const float a0 = wp[col];
        const float a1 = wp[C_DIM + col];
        const float a2 = wp[2 * C_DIM + col];
        g00 = fmaf(a0, a0, g00); g01 = fmaf(a0, a1, g01);
        g02 = fmaf(a0, a2, g02); g11 = fmaf(a1, a1, g11);
        g12 = fmaf(a1, a2, g12); g22 = fmaf(a2, a2, g22);
    }
#pragma unroll
    for (int off = 32; off; off >>= 1) {
        g00 += __shfl_xor(g00, off, 64);
        g01 += __shfl_xor(g01, off, 64);
        g02 += __shfl_xor(g02, off, 64);
        g11 += __shfl_xor(g11, off, 64);
        g12 += __shfl_xor(g12, off, 64);
        g22 += __shfl_xor(g22, off, 64);
    }
    if (l == 0) {
        float* gp = Gt + (size_t)c * 8;
        gp[0] = g00; gp[1] = g01; gp[2] = g02; gp[3] = g11;
        gp[4] = g12; gp[5] = g22; gp[6] = 0.f; gp[7] = 0.f;
    }
}

// ---------------------------------------------------------------------------
// Main kernel. One 16-lane group per batch element, 4 elements/wave.
// __launch_bounds__(256, 8): cap VGPR at 64 -> 8 waves/SIMD (32 waves/CU),
// ~2x the resident-wave count of all prior rounds. The kernel is
// latency-bound (VALU-cut and per-wave-ILP attacks both null); doubling
// resident waves is the remaining occupancy lever.
// Algebra (verified absmax=0): argmin_j ||u - im_j||^2
//   = argmin_j ( P_j^T G P_j - 2 P_j . v ),  v = W_t u,  G = W_t W_t^T.
// ---------------------------------------------------------------------------
__global__ __launch_bounds__(256, 8) void impact_kernel(
    const int*   __restrict__ user_ids,
    const int*   __restrict__ item_ids,
    const int*   __restrict__ concept_ids,
    const float* __restrict__ users_emb,   // (USER_N, 128)
    const float* __restrict__ item_resp,   // (ITEM_N * 14, 3)
    const float* __restrict__ W,           // (128, 3, 128)
    const int*   __restrict__ nb_mod,      // (ITEM_N,)
    const float* __restrict__ Gt,          // (128, 8) precomputed Gram
    float*       __restrict__ out)         // (B,)
{
    const int s = threadIdx.x & 15;                     // sublane in group
    const int b = blockIdx.x * 16 + (threadIdx.x >> 4); // element id

    const int uid = user_ids[b];
    const int iid = item_ids[b];
    const int cid = concept_ids[b];
    const int nb  = nb_mod[iid];

    // Branchless P load (lane s <-> modality j=s+1; lanes 12..15 clamp to 1,
    // masked to INF below). Issued early with everything else.
    const int jl = (s < 12) ? (s + 1) : 1;
    const float* pj = item_resp + ((size_t)iid * M_MOD + jl) * 3;
    const float p0 = pj[0], p1 = pj[1], p2 = pj[2];

    // Gram broadcast (L1-hit, 4 KB table).
    const float4* gp = (const float4*)(Gt + (size_t)cid * 8);
    const float4 gA = gp[0], gB = gp[1];

    // u row: 2 x float4 per lane (256 B coalesced runs per group).
    const float4* up = (const float4*)(users_emb + (size_t)uid * C_DIM);
    const float4 uA = up[s], uB = up[s + 16];
    // W_t = W[cid]: 3 rows x 512 B (L2-resident table).
    const float4* wp = (const float4*)(W + (size_t)cid * 3 * C_DIM);
    const float4 w0a = wp[s],      w0b = wp[16 + s];
    const float4 w1a = wp[32 + s], w1b = wp[48 + s];
    const float4 w2a = wp[64 + s], w2b = wp[80 + s];

    // v = W_t u over this lane's 8 columns (3 FMA per column).
    float v0 = 0.f, v1 = 0.f, v2 = 0.f;
#define COLV(uc, a0, a1, a2)                                                   \
    do {                                                                       \
        v0 = fmaf((a0), (uc), v0);                                             \
        v1 = fmaf((a1), (uc), v1);                                             \
        v2 = fmaf((a2), (uc), v2);                                             \
    } while (0)
    COLV(uA.x, w0a.x, w1a.x, w2a.x);
    COLV(uA.y, w0a.y, w1a.y, w2a.y);
    COLV(uA.z, w0a.z, w1a.z, w2a.z);
    COLV(uA.w, w0a.w, w1a.w, w2a.w);
    COLV(uB.x, w0b.x, w1b.x, w2b.x);
    COLV(uB.y, w0b.y, w1b.y, w2b.y);
    COLV(uB.z, w0b.z, w1b.z, w2b.z);
    COLV(uB.w, w0b.w, w1b.w, w2b.w);
#undef COLV

    // Butterfly-reduce the 3 v partials across the 16-lane group.
#pragma unroll
    for (int off = 8; off; off >>= 1) {
        v0 += __shfl_xor(v0, off, 64);
        v1 += __shfl_xor(v1, off, 64);
        v2 += __shfl_xor(v2, off, 64);
    }

    // Lane s scores modality j = s+1 (valid iff j <= nb; nb >= 2 so the min
    // is always finite).
    float m = INFINITY;
    if (s < 12 && (s + 1) <= nb) {
        const float dot = fmaf(p0, v0, fmaf(p1, v1, p2 * v2));
        float q = p0 * p0 * gA.x;                 // g00
        q = fmaf(p1 * p1, gA.w, q);               // g11
        q = fmaf(p2 * p2, gB.y, q);               // g22
        q = fmaf(2.0f * p0 * p1, gA.y, q);        // g01
        q = fmaf(2.0f * p0 * p2, gA.z, q);        // g02
        q = fmaf(2.0f * p1 * p2, gB.x, q);        // g12
        m = fmaf(-2.0f, dot, q);
    }
    // Group-wide min, then first-set-bit for jnp.argmin's lowest-index rule.
    float bm = m;
#pragma unroll
    for (int off = 8; off; off >>= 1)
        bm = fminf(bm, __shfl_xor(bm, off, 64));
    const unsigned long long mask = __ballot(m == bm);
    if (s == 0) {
        const int group = (threadIdx.x >> 4) & 3;
        const unsigned slice = (unsigned)((mask >> (group * 16)) & 0xffffu);
        const int jm1 = __builtin_ctz(slice);   // lane s <-> j=s+1
        out[b] = (float)jm1 / (float)(nb - 1) + 1.0f;
    }
}

// Fallback (ws unavailable): verified round-1/2 structure, inline Gram.
__global__ __launch_bounds__(256, 4) void impact_direct(
    const int*   __restrict__ user_ids,
    const int*   __restrict__ item_ids,
    const int*   __restrict__ concept_ids,
    const float* __restrict__ users_emb,
    const float* __restrict__ item_resp,
    const float* __restrict__ W,
    const int*   __restrict__ nb_mod,
    float*       __restrict__ out)
{
    const int s = threadIdx.x & 15;
    const int b = blockIdx.x * 16 + (threadIdx.x >> 4);

    const int uid = user_ids[b];
    const int iid = item_ids[b];
    const int cid = concept_ids[b];
    const int nb  = nb_mod[iid];

    const int jl = (s < 12) ? (s + 1) : 1;
    const float* pj = item_resp + ((size_t)iid * M_MOD + jl) * 3;
    const float p0 = pj[0], p1 = pj[1], p2 = pj[2];

    const float4* up = (const float4*)(users_emb + (size_t)uid * C_DIM);
    const float4 uA = up[s], uB = up[s + 16];
    const float4* wp = (const float4*)(W + (size_t)cid * 3 * C_DIM);
    const float4 w0a = wp[s],      w0b = wp[16 + s];
    const float4 w1a = wp[32 + s], w1b = wp[48 + s];
    const float4 w2a = wp[64 + s], w2b = wp[80 + s];

    float v0 = 0.f, v1 = 0.f, v2 = 0.f;
    float g00 = 0.f, g01 = 0.f, g02 = 0.f, g11 = 0.f, g12 = 0.f, g22 = 0.f;
#define COL(uc, a0, a1, a2)                                                    \
    do {                                                                       \
        v0  = fmaf((a0), (uc), v0);  v1  = fmaf((a1), (uc), v1);               \
        v2  = fmaf((a2), (uc), v2);                                            \
        g00 = fmaf((a0), (a0), g00); g01 = fmaf((a0), (a1), g01);              \
        g02 = fmaf((a0), (a2), g02); g11 = fmaf((a1), (a1), g11);              \
        g12 = fmaf((a1), (a2), g12); g22 = fmaf((a2), (a2), g22);              \
    } while (0)
    COL(uA.x, w0a.x, w1a.x, w2a.x);
    COL(uA.y, w0a.y, w1a.y, w2a.y);
    COL(uA.z, w0a.z, w1a.z, w2a.z);
    COL(uA.w, w0a.w, w1a.w, w2a.w);
    COL(uB.x, w0b.x, w1b.x, w2b.x);
    COL(uB.y, w0b.y, w1b.y, w2b.y);
    COL(uB.z, w0b.z, w1b.z, w2b.z);
    COL(uB.w, w0b.w, w1b.w, w2b.w);
#undef COL
#pragma unroll
    for (int off = 8; off; off >>= 1) {
        v0  += __shfl_xor(v0,  off, 64);
        v1  += __shfl_xor(v1,  off, 64);
        v2  += __shfl_xor(v2,  off, 64);
        g00 += __shfl_xor(g00, off, 64);
        g01 += __shfl_xor(g01, off, 64);
        g02 += __shfl_xor(g02, off, 64);
        g11 += __shfl_xor(g11, off, 64);
        g12 += __shfl_xor(g12, off, 64);
        g22 += __shfl_xor(g22, off, 64);
    }
    float m = INFINITY;
    if (s < 12 && (s + 1) <= nb) {
        const float dot = fmaf(p0, v0, fmaf(p1, v1, p2 * v2));
        float q = p0 * p0 * g00;
        q = fmaf(p1 * p1, g11, q);
        q = fmaf(p2 * p2, g22, q);
        q = fmaf(2.0f * p0 * p1, g01, q);
        q = fmaf(2.0f * p0 * p2, g02, q);
        q = fmaf(2.0f * p1 * p2, g12, q);
        m = fmaf(-2.0f, dot, q);
    }
    float bm = m;
#pragma unroll
    for (int off = 8; off; off >>= 1)
        bm = fminf(bm, __shfl_xor(bm, off, 64));
    const unsigned long long mask = __ballot(m == bm);
    if (s == 0) {
        const int group = (threadIdx.x >> 4) & 3;
        const unsigned slice = (unsigned)((mask >> (group * 16)) & 0xffffu);
        const int jm1 = __builtin_ctz(slice);
        out[b] = (float)jm1 / (float)(nb - 1) + 1.0f;
    }
}

extern "C" void kernel_launch(void* const* d_in, const int* in_sizes, int n_in,
                              void* d_out, int out_size, void* d_ws, size_t ws_size,
                              hipStream_t stream) {
    const int*   user_ids    = (const int*)d_in[0];
    const int*   item_ids    = (const int*)d_in[1];
    const int*   concept_ids = (const int*)d_in[2];
    const float* users_emb   = (const float*)d_in[3];
    const float* item_resp   = (const float*)d_in[4];
    const float* W           = (const float*)d_in[5];
    // d_in[6] = mask: unused — validity recomputed from nb_modalities.
    const int*   nb_mod      = (const int*)d_in[7];
    float*       out         = (float*)d_out;

    const size_t gram_bytes = (size_t)CONCEPT_N * 8 * sizeof(float); // 4 KB

    dim3 grid(B_TOTAL / 16), block(256);
    if (d_ws != nullptr && ws_size >= gram_bytes) {
        float* Gt = (float*)d_ws;
        gram_kernel<<<dim3(CONCEPT_N), dim3(64), 0, stream>>>(W, Gt);
        impact_kernel<<<grid, block, 0, stream>>>(
            user_ids, item_ids, concept_ids, users_emb, item_resp, W, nb_mod,
            Gt, out);
    } else {
        impact_direct<<<grid, block, 0, stream>>>(
            user_ids, item_ids, concept_ids, users_emb, item_resp, W, nb_mod,
            out);
    }
}